// Round 6
// baseline (645.231 us; speedup 1.0000x reference)
//
#include <hip/hip_runtime.h>
#include <hip/hip_bf16.h>

typedef __hip_bfloat16 bf16;
typedef __attribute__((ext_vector_type(8))) __bf16 bf16x8;
typedef __attribute__((ext_vector_type(4))) float f32x4;
typedef __attribute__((ext_vector_type(8))) short s16x8;

#define B_    8
#define S_    1024
#define H_    16
#define D_    128
#define HID_  2048
#define NQKV_ 2304
#define T_    8192

__device__ __forceinline__ void gload_lds16(const void* g, void* l) {
  __builtin_amdgcn_global_load_lds((const __attribute__((address_space(1))) void*)g,
                                   (__attribute__((address_space(3))) void*)l, 16, 0, 0);
}

// ---------------- cast fp32 -> bf16, 8 elems/thread ----------------
__global__ void cast_bf16_kernel(const float* __restrict__ src, bf16* __restrict__ dst, int n8) {
  const int i = blockIdx.x * 256 + threadIdx.x;
  if (i >= n8) return;
  const float4 a = ((const float4*)src)[2 * i];
  const float4 b = ((const float4*)src)[2 * i + 1];
  s16x8 o;
  o[0] = (short)__bfloat16_as_ushort(__float2bfloat16(a.x));
  o[1] = (short)__bfloat16_as_ushort(__float2bfloat16(a.y));
  o[2] = (short)__bfloat16_as_ushort(__float2bfloat16(a.z));
  o[3] = (short)__bfloat16_as_ushort(__float2bfloat16(a.w));
  o[4] = (short)__bfloat16_as_ushort(__float2bfloat16(b.x));
  o[5] = (short)__bfloat16_as_ushort(__float2bfloat16(b.y));
  o[6] = (short)__bfloat16_as_ushort(__float2bfloat16(b.z));
  o[7] = (short)__bfloat16_as_ushort(__float2bfloat16(b.w));
  ((s16x8*)dst)[i] = o;
}

// ------------- transpose + cast: src (R x C) f32 -> dst (C x R) bf16 -------------
__global__ void transpose_cast_kernel(const float* __restrict__ src, bf16* __restrict__ dst,
                                      int R, int C) {
  __shared__ float tile[32][33];
  const int tx = threadIdx.x & 31, ty = threadIdx.x >> 5;
  const int rt = blockIdx.y * 32, ct = blockIdx.x * 32;
#pragma unroll
  for (int k = 0; k < 4; ++k)
    tile[ty + 8 * k][tx] = src[(size_t)(rt + ty + 8 * k) * C + ct + tx];
  __syncthreads();
#pragma unroll
  for (int k = 0; k < 4; ++k)
    dst[(size_t)(ct + ty + 8 * k) * R + rt + tx] = __float2bfloat16(tile[tx][ty + 8 * k]);
}

// ------------- V transpose: QKV V-cols -> Vt[b][d][k] bf16 -------------
__global__ void transpose_v_kernel(const bf16* __restrict__ QKV, bf16* __restrict__ Vt) {
  __shared__ short t[64][72];
  const int kt = blockIdx.x, dt = blockIdx.y, b = blockIdx.z;
  const int r = threadIdx.x >> 3;        // 0..31
  const int c8 = (threadIdx.x & 7) * 8;  // 0,8..56
#pragma unroll
  for (int p = 0; p < 2; ++p) {
    const int row = p * 32 + r;
    const s16x8 v = *(const s16x8*)(QKV + (size_t)(b * S_ + kt * 64 + row) * NQKV_ +
                                    HID_ + D_ + dt * 64 + c8);
    *(s16x8*)&t[row][c8] = v;
  }
  __syncthreads();
#pragma unroll
  for (int p = 0; p < 2; ++p) {
    const int drow = p * 32 + r;
    s16x8 o;
#pragma unroll
    for (int j = 0; j < 8; ++j) o[j] = t[c8 + j][drow];
    *(s16x8*)(Vt + (size_t)(b * D_ + dt * 64 + drow) * S_ + kt * 64 + c8) = o;
  }
}

// ------------- GEMM: A (MxK bf16) * Bt(NxK bf16)^T + bias -> C (MxN) -------------
template <bool OUT_F32>
__global__ __launch_bounds__(256) void gemm_kernel(const bf16* __restrict__ A,
                                                   const bf16* __restrict__ Bt,
                                                   const float* __restrict__ bias,
                                                   void* __restrict__ Cout,
                                                   int M, int N, int K) {
  __shared__ bf16 As[128 * 32];
  __shared__ bf16 Bs[128 * 32];
  const int tid = threadIdx.x;
  const int lane = tid & 63;
  const int wave = tid >> 6;
  const int bn = blockIdx.x, bm = blockIdx.y;
  const int lrow = lane & 15, lk = lane >> 4;
  const int rbase = (wave >> 1) * 64;
  const int nbase = (wave & 1) * 64;
  f32x4 acc[4][4] = {};

  const int flat0 = wave * 1024 + (lane << 4);
  for (int kt = 0; kt < K; kt += 32) {
#pragma unroll
    for (int c = 0; c < 2; ++c) {
      const int flat = c * 4096 + flat0;
      const int row = flat >> 6;
      const int colb = flat & 63;
      gload_lds16((const char*)(A + (size_t)(bm * 128 + row) * K + kt) + colb,
                  (char*)As + c * 4096 + wave * 1024);
      gload_lds16((const char*)(Bt + (size_t)(bn * 128 + row) * K + kt) + colb,
                  (char*)Bs + c * 4096 + wave * 1024);
    }
    __syncthreads();
    bf16x8 af[4], bfr[4];
#pragma unroll
    for (int mi = 0; mi < 4; ++mi)
      af[mi] = *(const bf16x8*)(As + (size_t)(rbase + mi * 16 + lrow) * 32 + lk * 8);
#pragma unroll
    for (int ni = 0; ni < 4; ++ni)
      bfr[ni] = *(const bf16x8*)(Bs + (size_t)(nbase + ni * 16 + lrow) * 32 + lk * 8);
#pragma unroll
    for (int mi = 0; mi < 4; ++mi)
#pragma unroll
      for (int ni = 0; ni < 4; ++ni)
        acc[mi][ni] = __builtin_amdgcn_mfma_f32_16x16x32_bf16(af[mi], bfr[ni], acc[mi][ni], 0, 0, 0);
    __syncthreads();
  }
#pragma unroll
  for (int ni = 0; ni < 4; ++ni) {
    const int col = bn * 128 + nbase + ni * 16 + lrow;
    const float bv = bias[col];
#pragma unroll
    for (int mi = 0; mi < 4; ++mi) {
      const int row0 = bm * 128 + rbase + mi * 16 + lk * 4;
#pragma unroll
      for (int r = 0; r < 4; ++r) {
        const float v = acc[mi][ni][r] + bv;
        if (OUT_F32)
          ((float*)Cout)[(size_t)(row0 + r) * N + col] = v;
        else
          ((bf16*)Cout)[(size_t)(row0 + r) * N + col] = __float2bfloat16(v);
      }
    }
  }
}

// ------------- causal MQA flash attention v3: 1 wave / 16 q-rows, no LDS staging -------------
// grid (S/16 [qm reversed], H, B), 64 threads. K/V fragments read directly from
// global (L2-resident, shared across all 16 MQA heads). Only P (2KB) in LDS;
// zero barriers — waves fully decoupled.
__global__ __launch_bounds__(64) void attn_kernel(const bf16* __restrict__ QKV,
                                                  const bf16* __restrict__ Vt,
                                                  bf16* __restrict__ aout) {
  const int qm = (int)gridDim.x - 1 - (int)blockIdx.x;  // 0..63, long blocks first
  const int h = blockIdx.y;
  const int b = blockIdx.z;
  const int lane = threadIdx.x;
  const int lrow = lane & 15, lk = lane >> 4;

  __shared__ char Ps[2048];  // P: 16 rows x 128B, XOR-swizzled

  const bf16* qkv_b = QKV + (size_t)b * S_ * NQKV_;
  const bf16* vt_b = Vt + (size_t)b * D_ * S_;

  // Q A-fragments: row = qm*16 + lrow, d = kk*32 + lk*8 (contiguous 16B)
  bf16x8 qf[4];
#pragma unroll
  for (int kk = 0; kk < 4; ++kk)
    qf[kk] = *(const bf16x8*)(qkv_b + (size_t)(qm * 16 + lrow) * NQKV_ + h * D_ + kk * 32 + lk * 8);

  float mrun[4], lrun[4];
  f32x4 Oacc[8] = {};
#pragma unroll
  for (int r = 0; r < 4; ++r) { mrun[r] = -1e30f; lrun[r] = 0.f; }
  const float scale = 0.08838834764831845f;

  const int nkt = (qm >> 2) + 1;
  for (int kt = 0; kt < nkt; ++kt) {
    // QK^T: B-frag = K[kcol][d], kcol = kt*64+cf*16+lrow, d = kk*32+lk*8 (16B contiguous)
    f32x4 sc[4];
#pragma unroll
    for (int cf = 0; cf < 4; ++cf) {
      f32x4 s = {0.f, 0.f, 0.f, 0.f};
      const bf16* krow = qkv_b + (size_t)(kt * 64 + cf * 16 + lrow) * NQKV_ + HID_;
#pragma unroll
      for (int kk = 0; kk < 4; ++kk) {
        const bf16x8 kf = *(const bf16x8*)(krow + kk * 32 + lk * 8);
        s = __builtin_amdgcn_mfma_f32_16x16x32_bf16(qf[kk], kf, s, 0, 0, 0);
      }
      sc[cf] = s;
    }

    // scale + causal mask (only the last tile has masked elements)
    const bool last = (kt == nkt - 1);
#pragma unroll
    for (int cf = 0; cf < 4; ++cf)
#pragma unroll
      for (int r = 0; r < 4; ++r) {
        float v = sc[cf][r] * scale;
        if (last && (kt * 64 + cf * 16 + lrow > qm * 16 + lk * 4 + r)) v = -1e30f;
        sc[cf][r] = v;
      }

    // online softmax: reduce across the 16-lane column group (lanes sharing lk)
    float corr[4];
#pragma unroll
    for (int r = 0; r < 4; ++r) {
      float mv = fmaxf(fmaxf(sc[0][r], sc[1][r]), fmaxf(sc[2][r], sc[3][r]));
#pragma unroll
      for (int xm = 1; xm < 16; xm <<= 1) mv = fmaxf(mv, __shfl_xor(mv, xm, 64));
      const float mn = fmaxf(mrun[r], mv);
      corr[r] = __expf(mrun[r] - mn);
      mrun[r] = mn;
    }
    float rsum[4] = {0.f, 0.f, 0.f, 0.f};
#pragma unroll
    for (int cf = 0; cf < 4; ++cf)
#pragma unroll
      for (int r = 0; r < 4; ++r) {
        const float p = __expf(sc[cf][r] - mrun[r]);
        sc[cf][r] = p;
        rsum[r] += p;
      }
#pragma unroll
    for (int r = 0; r < 4; ++r) {
#pragma unroll
      for (int xm = 1; xm < 16; xm <<= 1) rsum[r] += __shfl_xor(rsum[r], xm, 64);
      lrun[r] = lrun[r] * corr[r] + rsum[r];
    }
#pragma unroll
    for (int f = 0; f < 8; ++f)
#pragma unroll
      for (int r = 0; r < 4; ++r) Oacc[f][r] *= corr[r];

    // P -> LDS (bf16, swizzled); within-wave sync only (no barrier)
#pragma unroll
    for (int cf = 0; cf < 4; ++cf)
#pragma unroll
      for (int r = 0; r < 4; ++r) {
        const int prow = lk * 4 + r;
        const int byte = prow * 128 + (((cf * 16 + lrow) * 2) ^ ((prow & 7) << 4));
        *(bf16*)(Ps + byte) = __float2bfloat16(sc[cf][r]);
      }
    asm volatile("s_waitcnt lgkmcnt(0)" ::: "memory");
    __builtin_amdgcn_sched_barrier(0);

    bf16x8 pf[2];
#pragma unroll
    for (int ks = 0; ks < 2; ++ks)
      pf[ks] = *(const bf16x8*)(Ps + lrow * 128 + ((ks * 64 + lk * 16) ^ ((lrow & 7) << 4)));
    asm volatile("s_waitcnt lgkmcnt(0)" ::: "memory");
    __builtin_amdgcn_sched_barrier(0);

    // PV: B-frag = Vt[d][k], d = f*16+lrow, k = kt*64 + ks*32 + lk*8 (16B contiguous)
#pragma unroll
    for (int f = 0; f < 8; ++f) {
      const bf16* vrow = vt_b + (size_t)(f * 16 + lrow) * S_ + kt * 64;
#pragma unroll
      for (int ks = 0; ks < 2; ++ks) {
        const bf16x8 vf = *(const bf16x8*)(vrow + ks * 32 + lk * 8);
        Oacc[f] = __builtin_amdgcn_mfma_f32_16x16x32_bf16(pf[ks], vf, Oacc[f], 0, 0, 0);
      }
    }
  }

  // epilogue: divide by l, write attn (token-major, col = h*128 + d)
#pragma unroll
  for (int f = 0; f < 8; ++f)
#pragma unroll
    for (int r = 0; r < 4; ++r) {
      const int token = b * S_ + qm * 16 + lk * 4 + r;
      const int col = h * D_ + f * 16 + lrow;
      aout[(size_t)token * HID_ + col] = __float2bfloat16(Oacc[f][r] / lrun[r]);
    }
}

extern "C" void kernel_launch(void* const* d_in, const int* in_sizes, int n_in,
                              void* d_out, int out_size, void* d_ws, size_t ws_size,
                              hipStream_t stream) {
  const float* hidden = (const float*)d_in[0];
  const float* w_attn = (const float*)d_in[1];
  const float* b_attn = (const float*)d_in[2];
  const float* w_proj = (const float*)d_in[3];
  const float* b_proj = (const float*)d_in[4];

  char* ws = (char*)d_ws;
  char* dob = (char*)d_out;

  // ws: [0,33.5M) Xbf (bf16 hidden, later attn out); [33.5M,42M) WpT
  bf16* Xbf = (bf16*)ws;
  bf16* WpT = (bf16*)(ws + 33554432);
  // d_out as scratch (fully overwritten by GEMM2):
  // [0,37.75M) QKV bf16; [37.75M,47.2M) WaT; [48M,50M) Vt bf16
  bf16* QKV = (bf16*)dob;
  bf16* WaT = (bf16*)(dob + 37748736);
  bf16* Vt = (bf16*)(dob + 50331648);

  cast_bf16_kernel<<<(T_ * HID_) / 8 / 256, 256, 0, stream>>>(hidden, Xbf, (T_ * HID_) / 8);
  transpose_cast_kernel<<<dim3(NQKV_ / 32, HID_ / 32), 256, 0, stream>>>(w_attn, WaT, HID_, NQKV_);
  transpose_cast_kernel<<<dim3(HID_ / 32, HID_ / 32), 256, 0, stream>>>(w_proj, WpT, HID_, HID_);

  gemm_kernel<false><<<dim3(NQKV_ / 128, T_ / 128), 256, 0, stream>>>(
      Xbf, WaT, b_attn, QKV, T_, NQKV_, HID_);

  transpose_v_kernel<<<dim3(S_ / 64, D_ / 64, B_), 256, 0, stream>>>(QKV, Vt);

  attn_kernel<<<dim3(S_ / 16, H_, B_), 64, 0, stream>>>(QKV, Vt, Xbf);

  gemm_kernel<true><<<dim3(HID_ / 128, T_ / 128), 256, 0, stream>>>(
      Xbf, WpT, b_proj, (float*)d_out, T_, HID_, HID_);
}

// Round 10
// 452.340 us; speedup vs baseline: 1.4264x; 1.4264x over previous
//
#include <hip/hip_runtime.h>
#include <hip/hip_bf16.h>

typedef __hip_bfloat16 bf16;
typedef __attribute__((ext_vector_type(8))) __bf16 bf16x8;
typedef __attribute__((ext_vector_type(4))) float f32x4;
typedef __attribute__((ext_vector_type(8))) short s16x8;

#define B_    8
#define S_    1024
#define H_    16
#define D_    128
#define HID_  2048
#define NQKV_ 2304
#define T_    8192

__device__ __forceinline__ void gload_lds16(const void* g, void* l) {
  __builtin_amdgcn_global_load_lds((const __attribute__((address_space(1))) void*)g,
                                   (__attribute__((address_space(3))) void*)l, 16, 0, 0);
}

// ---------------- cast fp32 -> bf16, 8 elems/thread ----------------
__global__ void cast_bf16_kernel(const float* __restrict__ src, bf16* __restrict__ dst, int n8) {
  const int i = blockIdx.x * 256 + threadIdx.x;
  if (i >= n8) return;
  const float4 a = ((const float4*)src)[2 * i];
  const float4 b = ((const float4*)src)[2 * i + 1];
  s16x8 o;
  o[0] = (short)__bfloat16_as_ushort(__float2bfloat16(a.x));
  o[1] = (short)__bfloat16_as_ushort(__float2bfloat16(a.y));
  o[2] = (short)__bfloat16_as_ushort(__float2bfloat16(a.z));
  o[3] = (short)__bfloat16_as_ushort(__float2bfloat16(a.w));
  o[4] = (short)__bfloat16_as_ushort(__float2bfloat16(b.x));
  o[5] = (short)__bfloat16_as_ushort(__float2bfloat16(b.y));
  o[6] = (short)__bfloat16_as_ushort(__float2bfloat16(b.z));
  o[7] = (short)__bfloat16_as_ushort(__float2bfloat16(b.w));
  ((s16x8*)dst)[i] = o;
}

// ------------- transpose + cast: src (R x C) f32 -> dst (C x R) bf16 -------------
__global__ void transpose_cast_kernel(const float* __restrict__ src, bf16* __restrict__ dst,
                                      int R, int C) {
  __shared__ float tile[32][33];
  const int tx = threadIdx.x & 31, ty = threadIdx.x >> 5;
  const int rt = blockIdx.y * 32, ct = blockIdx.x * 32;
#pragma unroll
  for (int k = 0; k < 4; ++k)
    tile[ty + 8 * k][tx] = src[(size_t)(rt + ty + 8 * k) * C + ct + tx];
  __syncthreads();
#pragma unroll
  for (int k = 0; k < 4; ++k)
    dst[(size_t)(ct + ty + 8 * k) * R + rt + tx] = __float2bfloat16(tile[tx][ty + 8 * k]);
}

// ------------- V transpose: QKV V-cols -> Vt[b][d][k] bf16 -------------
__global__ void transpose_v_kernel(const bf16* __restrict__ QKV, bf16* __restrict__ Vt) {
  __shared__ short t[64][72];
  const int kt = blockIdx.x, dt = blockIdx.y, b = blockIdx.z;
  const int r = threadIdx.x >> 3;        // 0..31
  const int c8 = (threadIdx.x & 7) * 8;  // 0,8..56
#pragma unroll
  for (int p = 0; p < 2; ++p) {
    const int row = p * 32 + r;
    const s16x8 v = *(const s16x8*)(QKV + (size_t)(b * S_ + kt * 64 + row) * NQKV_ +
                                    HID_ + D_ + dt * 64 + c8);
    *(s16x8*)&t[row][c8] = v;
  }
  __syncthreads();
#pragma unroll
  for (int p = 0; p < 2; ++p) {
    const int drow = p * 32 + r;
    s16x8 o;
#pragma unroll
    for (int j = 0; j < 8; ++j) o[j] = t[c8 + j][drow];
    *(s16x8*)(Vt + (size_t)(b * D_ + dt * 64 + drow) * S_ + kt * 64 + c8) = o;
  }
}

// ------------- GEMM: A (MxK bf16) * Bt(NxK bf16)^T + bias -> C (MxN) -------------
template <bool OUT_F32>
__global__ __launch_bounds__(256) void gemm_kernel(const bf16* __restrict__ A,
                                                   const bf16* __restrict__ Bt,
                                                   const float* __restrict__ bias,
                                                   void* __restrict__ Cout,
                                                   int M, int N, int K) {
  __shared__ bf16 As[128 * 32];
  __shared__ bf16 Bs[128 * 32];
  const int tid = threadIdx.x;
  const int lane = tid & 63;
  const int wave = tid >> 6;
  const int bn = blockIdx.x, bm = blockIdx.y;
  const int lrow = lane & 15, lk = lane >> 4;
  const int rbase = (wave >> 1) * 64;
  const int nbase = (wave & 1) * 64;
  f32x4 acc[4][4] = {};

  const int flat0 = wave * 1024 + (lane << 4);
  for (int kt = 0; kt < K; kt += 32) {
#pragma unroll
    for (int c = 0; c < 2; ++c) {
      const int flat = c * 4096 + flat0;
      const int row = flat >> 6;
      const int colb = flat & 63;
      gload_lds16((const char*)(A + (size_t)(bm * 128 + row) * K + kt) + colb,
                  (char*)As + c * 4096 + wave * 1024);
      gload_lds16((const char*)(Bt + (size_t)(bn * 128 + row) * K + kt) + colb,
                  (char*)Bs + c * 4096 + wave * 1024);
    }
    __syncthreads();
    bf16x8 af[4], bfr[4];
#pragma unroll
    for (int mi = 0; mi < 4; ++mi)
      af[mi] = *(const bf16x8*)(As + (size_t)(rbase + mi * 16 + lrow) * 32 + lk * 8);
#pragma unroll
    for (int ni = 0; ni < 4; ++ni)
      bfr[ni] = *(const bf16x8*)(Bs + (size_t)(nbase + ni * 16 + lrow) * 32 + lk * 8);
#pragma unroll
    for (int mi = 0; mi < 4; ++mi)
#pragma unroll
      for (int ni = 0; ni < 4; ++ni)
        acc[mi][ni] = __builtin_amdgcn_mfma_f32_16x16x32_bf16(af[mi], bfr[ni], acc[mi][ni], 0, 0, 0);
    __syncthreads();
  }
#pragma unroll
  for (int ni = 0; ni < 4; ++ni) {
    const int col = bn * 128 + nbase + ni * 16 + lrow;
    const float bv = bias[col];
#pragma unroll
    for (int mi = 0; mi < 4; ++mi) {
      const int row0 = bm * 128 + rbase + mi * 16 + lk * 4;
#pragma unroll
      for (int r = 0; r < 4; ++r) {
        const float v = acc[mi][ni][r] + bv;
        if (OUT_F32)
          ((float*)Cout)[(size_t)(row0 + r) * N + col] = v;
        else
          ((bf16*)Cout)[(size_t)(row0 + r) * N + col] = __float2bfloat16(v);
      }
    }
  }
}

// ------------- causal MQA flash attention v4: double-buffered K/V, counted vmcnt -------------
// grid (S/64 [qt reversed], H, B); 256 threads = 4 waves, each wave owns 16 q-rows.
// LDS (72KB): K buffers @ 0 / 16K (64x256B swz), V buffers @ 32K / 48K (128x128B swz),
//             P @ 64K + wave*2K. 2 blocks/CU.
// Schedule (T3 minimum-2-phase): STAGE(next); vmcnt(8); barrier; compute(cur); barrier.
__global__ __launch_bounds__(256) void attn_kernel(const bf16* __restrict__ QKV,
                                                   const bf16* __restrict__ Vt,
                                                   bf16* __restrict__ aout) {
  const int qt = gridDim.x - 1 - blockIdx.x;  // long blocks first
  const int h = blockIdx.y;
  const int b = blockIdx.z;
  const int tid = threadIdx.x;
  const int lane = tid & 63;
  const int wave = tid >> 6;
  const int lrow = lane & 15, lk = lane >> 4;

  __shared__ char lds[73728];
  char* Ps = lds + 65536 + wave * 2048;

  const char* qkv_b = (const char*)QKV + (size_t)b * S_ * (NQKV_ * 2);
  const char* vt_b = (const char*)Vt + (size_t)b * D_ * S_ * 2;
  const int Xw = wave * 4096;

  // per-wave staging offsets (pre-swizzled global source, linear LDS dest)
  int koff[4], kcb[4], voff[4], vcb[4];
#pragma unroll
  for (int o = 0; o < 4; ++o) {
    const int X = Xw + o * 1024 + lane * 16;
    const int r = X >> 8;
    kcb[o] = (X & 255) ^ ((r & 7) << 4);
    koff[o] = r;
    const int d = X >> 7;
    vcb[o] = (X & 127) ^ ((d & 7) << 4);
    voff[o] = d;
  }

#define STAGE_K(kbuf_off, kt_)                                                         \
  _Pragma("unroll") for (int o = 0; o < 4; ++o)                                        \
      gload_lds16(qkv_b + (size_t)((kt_) * 64 + koff[o]) * (NQKV_ * 2) + HID_ * 2 +    \
                      kcb[o],                                                          \
                  lds + (kbuf_off) + Xw + o * 1024);
#define STAGE_V(vbuf_off, kt_)                                                         \
  _Pragma("unroll") for (int o = 0; o < 4; ++o)                                        \
      gload_lds16(vt_b + (size_t)voff[o] * (S_ * 2) + (kt_) * 128 + vcb[o],            \
                  lds + (vbuf_off) + Xw + o * 1024);

  // ---- stage Q into K-buffer 0, read to regs ----
#pragma unroll
  for (int o = 0; o < 4; ++o)
    gload_lds16(qkv_b + (size_t)(qt * 64 + koff[o]) * (NQKV_ * 2) + h * 256 + kcb[o],
                lds + Xw + o * 1024);
  asm volatile("s_waitcnt vmcnt(0)" ::: "memory");
  __builtin_amdgcn_s_barrier();

  bf16x8 qf[4];
  {
    const int row = wave * 16 + lrow;
#pragma unroll
    for (int kk = 0; kk < 4; ++kk)
      qf[kk] = *(const bf16x8*)(lds + row * 256 + ((kk * 64 + lk * 16) ^ ((row & 7) << 4)));
  }
  asm volatile("s_waitcnt lgkmcnt(0)" ::: "memory");
  __builtin_amdgcn_sched_barrier(0);
  __builtin_amdgcn_s_barrier();  // all waves done reading Q before t0 staging

  // ---- prologue: stage tile 0 into buffer 0 ----
  STAGE_K(0, 0);
  STAGE_V(32768, 0);

  float mrun[4], lrun[4];
  f32x4 Oacc[8] = {};
#pragma unroll
  for (int r = 0; r < 4; ++r) { mrun[r] = -1e30f; lrun[r] = 0.f; }
  const float scale = 0.08838834764831845f;

  for (int kt = 0; kt <= qt; ++kt) {
    const int cur = kt & 1;
    const int kcur = cur * 16384;           // current K buffer offset
    const int vcur = 32768 + cur * 16384;   // current V buffer offset
    // stage next tile into the other buffer; counted vmcnt keeps them in flight
    if (kt < qt) {
      STAGE_K(kcur ^ 16384, kt + 1);
      STAGE_V(vcur ^ 16384, kt + 1);
      asm volatile("s_waitcnt vmcnt(8)" ::: "memory");  // cur tile's 8 loads done
    } else {
      asm volatile("s_waitcnt vmcnt(0)" ::: "memory");
    }
    __builtin_amdgcn_s_barrier();  // cur tile visible to all waves
    __builtin_amdgcn_sched_barrier(0);

    // QK^T: A = Q rows, B = K^T (16 MFMAs)
    f32x4 sc[4];
#pragma unroll
    for (int cf = 0; cf < 4; ++cf) {
      f32x4 s = {0.f, 0.f, 0.f, 0.f};
      const int row = cf * 16 + lrow;
#pragma unroll
      for (int kk = 0; kk < 4; ++kk) {
        const bf16x8 kf =
            *(const bf16x8*)(lds + kcur + row * 256 + ((kk * 64 + lk * 16) ^ ((row & 7) << 4)));
        s = __builtin_amdgcn_mfma_f32_16x16x32_bf16(qf[kk], kf, s, 0, 0, 0);
      }
      sc[cf] = s;
    }

    const bool diag = (kt == qt);
#pragma unroll
    for (int cf = 0; cf < 4; ++cf)
#pragma unroll
      for (int r = 0; r < 4; ++r) {
        float v = sc[cf][r] * scale;
        if (diag && (cf * 16 + lrow > wave * 16 + lk * 4 + r)) v = -1e30f;
        sc[cf][r] = v;
      }

    // online softmax (wave-parallel butterfly over 16-lane column groups)
    float corr[4];
#pragma unroll
    for (int r = 0; r < 4; ++r) {
      float mv = fmaxf(fmaxf(sc[0][r], sc[1][r]), fmaxf(sc[2][r], sc[3][r]));
#pragma unroll
      for (int xm = 1; xm < 16; xm <<= 1) mv = fmaxf(mv, __shfl_xor(mv, xm, 64));
      const float mn = fmaxf(mrun[r], mv);
      corr[r] = __expf(mrun[r] - mn);
      mrun[r] = mn;
    }
    float rsum[4] = {0.f, 0.f, 0.f, 0.f};
#pragma unroll
    for (int cf = 0; cf < 4; ++cf)
#pragma unroll
      for (int r = 0; r < 4; ++r) {
        const float p = __expf(sc[cf][r] - mrun[r]);
        sc[cf][r] = p;
        rsum[r] += p;
      }
#pragma unroll
    for (int r = 0; r < 4; ++r) {
#pragma unroll
      for (int xm = 1; xm < 16; xm <<= 1) rsum[r] += __shfl_xor(rsum[r], xm, 64);
      lrun[r] = lrun[r] * corr[r] + rsum[r];
    }
#pragma unroll
    for (int f = 0; f < 8; ++f)
#pragma unroll
      for (int r = 0; r < 4; ++r) Oacc[f][r] *= corr[r];

    // P -> per-wave LDS (bf16, swizzled); within-wave lgkm sync only
#pragma unroll
    for (int cf = 0; cf < 4; ++cf)
#pragma unroll
      for (int r = 0; r < 4; ++r) {
        const int prow = lk * 4 + r;
        const int byte = prow * 128 + (((cf * 16 + lrow) * 2) ^ ((prow & 7) << 4));
        *(bf16*)(Ps + byte) = __float2bfloat16(sc[cf][r]);
      }
    asm volatile("s_waitcnt lgkmcnt(0)" ::: "memory");
    __builtin_amdgcn_sched_barrier(0);

    bf16x8 pf[2];
#pragma unroll
    for (int ks = 0; ks < 2; ++ks)
      pf[ks] = *(const bf16x8*)(Ps + lrow * 128 + ((ks * 64 + lk * 16) ^ ((lrow & 7) << 4)));
    asm volatile("s_waitcnt lgkmcnt(0)" ::: "memory");
    __builtin_amdgcn_sched_barrier(0);

    // PV: A = P rows, B = Vt rows as V columns (16 MFMAs)
#pragma unroll
    for (int f = 0; f < 8; ++f) {
      const int d = f * 16 + lrow;
#pragma unroll
      for (int ks = 0; ks < 2; ++ks) {
        const bf16x8 vf =
            *(const bf16x8*)(lds + vcur + d * 128 + ((ks * 64 + lk * 16) ^ ((d & 7) << 4)));
        Oacc[f] = __builtin_amdgcn_mfma_f32_16x16x32_bf16(pf[ks], vf, Oacc[f], 0, 0, 0);
      }
    }
    __builtin_amdgcn_s_barrier();  // all waves done reading cur before it's restaged
  }

  // epilogue: divide by l, write attn (token-major, col = h*128 + d)
#pragma unroll
  for (int f = 0; f < 8; ++f)
#pragma unroll
    for (int r = 0; r < 4; ++r) {
      const int token = b * S_ + qt * 64 + wave * 16 + lk * 4 + r;
      const int col = h * D_ + f * 16 + lrow;
      aout[(size_t)token * HID_ + col] = __float2bfloat16(Oacc[f][r] / lrun[r]);
    }
#undef STAGE_K
#undef STAGE_V
}

extern "C" void kernel_launch(void* const* d_in, const int* in_sizes, int n_in,
                              void* d_out, int out_size, void* d_ws, size_t ws_size,
                              hipStream_t stream) {
  const float* hidden = (const float*)d_in[0];
  const float* w_attn = (const float*)d_in[1];
  const float* b_attn = (const float*)d_in[2];
  const float* w_proj = (const float*)d_in[3];
  const float* b_proj = (const float*)d_in[4];

  char* ws = (char*)d_ws;
  char* dob = (char*)d_out;

  // ws: [0,33.5M) Xbf (bf16 hidden, later attn out); [33.5M,42M) WpT
  bf16* Xbf = (bf16*)ws;
  bf16* WpT = (bf16*)(ws + 33554432);
  // d_out as scratch (fully overwritten by GEMM2):
  // [0,37.75M) QKV bf16; [37.75M,47.2M) WaT; [48M,50M) Vt bf16
  bf16* QKV = (bf16*)dob;
  bf16* WaT = (bf16*)(dob + 37748736);
  bf16* Vt = (bf16*)(dob + 50331648);

  cast_bf16_kernel<<<(T_ * HID_) / 8 / 256, 256, 0, stream>>>(hidden, Xbf, (T_ * HID_) / 8);
  transpose_cast_kernel<<<dim3(NQKV_ / 32, HID_ / 32), 256, 0, stream>>>(w_attn, WaT, HID_, NQKV_);
  transpose_cast_kernel<<<dim3(HID_ / 32, HID_ / 32), 256, 0, stream>>>(w_proj, WpT, HID_, HID_);

  gemm_kernel<false><<<dim3(NQKV_ / 128, T_ / 128), 256, 0, stream>>>(
      Xbf, WaT, b_attn, QKV, T_, NQKV_, HID_);

  transpose_v_kernel<<<dim3(S_ / 64, D_ / 64, B_), 256, 0, stream>>>(QKV, Vt);

  attn_kernel<<<dim3(S_ / 64, H_, B_), 256, 0, stream>>>(QKV, Vt, Xbf);

  gemm_kernel<true><<<dim3(HID_ / 128, T_ / 128), 256, 0, stream>>>(
      Xbf, WpT, b_proj, (float*)d_out, T_, HID_, HID_);
}

// Round 11
// 397.282 us; speedup vs baseline: 1.6241x; 1.1386x over previous
//
#include <hip/hip_runtime.h>
#include <hip/hip_bf16.h>

typedef __hip_bfloat16 bf16;
typedef __attribute__((ext_vector_type(8))) __bf16 bf16x8;
typedef __attribute__((ext_vector_type(4))) float f32x4;
typedef __attribute__((ext_vector_type(16))) float f32x16;
typedef __attribute__((ext_vector_type(8))) short s16x8;
typedef __attribute__((ext_vector_type(4))) unsigned u32x4;

#define B_    8
#define S_    1024
#define H_    16
#define D_    128
#define HID_  2048
#define NQKV_ 2304
#define T_    8192

__device__ __forceinline__ void gload_lds16(const void* g, void* l) {
  __builtin_amdgcn_global_load_lds((const __attribute__((address_space(1))) void*)g,
                                   (__attribute__((address_space(3))) void*)l, 16, 0, 0);
}

__device__ __forceinline__ unsigned pack_bf16(float lo, float hi) {
  return ((unsigned)__bfloat16_as_ushort(__float2bfloat16(hi)) << 16) |
         (unsigned)__bfloat16_as_ushort(__float2bfloat16(lo));
}

// ---------------- cast fp32 -> bf16, 8 elems/thread ----------------
__global__ void cast_bf16_kernel(const float* __restrict__ src, bf16* __restrict__ dst, int n8) {
  const int i = blockIdx.x * 256 + threadIdx.x;
  if (i >= n8) return;
  const float4 a = ((const float4*)src)[2 * i];
  const float4 b = ((const float4*)src)[2 * i + 1];
  s16x8 o;
  o[0] = (short)__bfloat16_as_ushort(__float2bfloat16(a.x));
  o[1] = (short)__bfloat16_as_ushort(__float2bfloat16(a.y));
  o[2] = (short)__bfloat16_as_ushort(__float2bfloat16(a.z));
  o[3] = (short)__bfloat16_as_ushort(__float2bfloat16(a.w));
  o[4] = (short)__bfloat16_as_ushort(__float2bfloat16(b.x));
  o[5] = (short)__bfloat16_as_ushort(__float2bfloat16(b.y));
  o[6] = (short)__bfloat16_as_ushort(__float2bfloat16(b.z));
  o[7] = (short)__bfloat16_as_ushort(__float2bfloat16(b.w));
  ((s16x8*)dst)[i] = o;
}

// ------------- transpose + cast: src (R x C) f32 -> dst (C x R) bf16 -------------
__global__ void transpose_cast_kernel(const float* __restrict__ src, bf16* __restrict__ dst,
                                      int R, int C) {
  __shared__ float tile[32][33];
  const int tx = threadIdx.x & 31, ty = threadIdx.x >> 5;
  const int rt = blockIdx.y * 32, ct = blockIdx.x * 32;
#pragma unroll
  for (int k = 0; k < 4; ++k)
    tile[ty + 8 * k][tx] = src[(size_t)(rt + ty + 8 * k) * C + ct + tx];
  __syncthreads();
#pragma unroll
  for (int k = 0; k < 4; ++k)
    dst[(size_t)(ct + ty + 8 * k) * R + rt + tx] = __float2bfloat16(tile[tx][ty + 8 * k]);
}

// ------------- V transpose: QKV V-cols -> Vt[b][d][k] bf16 -------------
__global__ void transpose_v_kernel(const bf16* __restrict__ QKV, bf16* __restrict__ Vt) {
  __shared__ short t[64][72];
  const int kt = blockIdx.x, dt = blockIdx.y, b = blockIdx.z;
  const int r = threadIdx.x >> 3;
  const int c8 = (threadIdx.x & 7) * 8;
#pragma unroll
  for (int p = 0; p < 2; ++p) {
    const int row = p * 32 + r;
    const s16x8 v = *(const s16x8*)(QKV + (size_t)(b * S_ + kt * 64 + row) * NQKV_ +
                                    HID_ + D_ + dt * 64 + c8);
    *(s16x8*)&t[row][c8] = v;
  }
  __syncthreads();
#pragma unroll
  for (int p = 0; p < 2; ++p) {
    const int drow = p * 32 + r;
    s16x8 o;
#pragma unroll
    for (int j = 0; j < 8; ++j) o[j] = t[c8 + j][drow];
    *(s16x8*)(Vt + (size_t)(b * D_ + dt * 64 + drow) * S_ + kt * 64 + c8) = o;
  }
}

// ------------- GEMM: A (MxK bf16) * Bt(NxK bf16)^T + bias -> C (MxN) -------------
template <bool OUT_F32>
__global__ __launch_bounds__(256) void gemm_kernel(const bf16* __restrict__ A,
                                                   const bf16* __restrict__ Bt,
                                                   const float* __restrict__ bias,
                                                   void* __restrict__ Cout,
                                                   int M, int N, int K) {
  __shared__ bf16 As[128 * 32];
  __shared__ bf16 Bs[128 * 32];
  const int tid = threadIdx.x;
  const int lane = tid & 63;
  const int wave = tid >> 6;
  const int bn = blockIdx.x, bm = blockIdx.y;
  const int lrow = lane & 15, lk = lane >> 4;
  const int rbase = (wave >> 1) * 64;
  const int nbase = (wave & 1) * 64;
  f32x4 acc[4][4] = {};

  const int flat0 = wave * 1024 + (lane << 4);
  for (int kt = 0; kt < K; kt += 32) {
#pragma unroll
    for (int c = 0; c < 2; ++c) {
      const int flat = c * 4096 + flat0;
      const int row = flat >> 6;
      const int colb = flat & 63;
      gload_lds16((const char*)(A + (size_t)(bm * 128 + row) * K + kt) + colb,
                  (char*)As + c * 4096 + wave * 1024);
      gload_lds16((const char*)(Bt + (size_t)(bn * 128 + row) * K + kt) + colb,
                  (char*)Bs + c * 4096 + wave * 1024);
    }
    __syncthreads();
    bf16x8 af[4], bfr[4];
#pragma unroll
    for (int mi = 0; mi < 4; ++mi)
      af[mi] = *(const bf16x8*)(As + (size_t)(rbase + mi * 16 + lrow) * 32 + lk * 8);
#pragma unroll
    for (int ni = 0; ni < 4; ++ni)
      bfr[ni] = *(const bf16x8*)(Bs + (size_t)(nbase + ni * 16 + lrow) * 32 + lk * 8);
#pragma unroll
    for (int mi = 0; mi < 4; ++mi)
#pragma unroll
      for (int ni = 0; ni < 4; ++ni)
        acc[mi][ni] = __builtin_amdgcn_mfma_f32_16x16x32_bf16(af[mi], bfr[ni], acc[mi][ni], 0, 0, 0);
    __syncthreads();
  }
#pragma unroll
  for (int ni = 0; ni < 4; ++ni) {
    const int col = bn * 128 + nbase + ni * 16 + lrow;
    const float bv = bias[col];
#pragma unroll
    for (int mi = 0; mi < 4; ++mi) {
      const int row0 = bm * 128 + rbase + mi * 16 + lk * 4;
#pragma unroll
      for (int r = 0; r < 4; ++r) {
        const float v = acc[mi][ni][r] + bv;
        if (OUT_F32)
          ((float*)Cout)[(size_t)(row0 + r) * N + col] = v;
        else
          ((bf16*)Cout)[(size_t)(row0 + r) * N + col] = __float2bfloat16(v);
      }
    }
  }
}

// ------------- causal MQA flash attention v5 -------------
// 4 waves x 32 q-rows (128/block). 32x32x16 MFMA, swapped QK^T (S^T = K·Q^T):
// lane owns q = lane&31; k lives in regs (+partner lane^32) -> in-register softmax.
// P packed to bf16 in-register, redistributed via shfl_xor(32) into PV A-frags.
// K/V double-buffered LDS, counted vmcnt(8). defer-max THR=8. No P LDS.
// LDS 64KB: K @0/16K (64x256B, xor (r&15)<<4), V @32K/48K (128x128B, xor (d&7)<<4).
__global__ __launch_bounds__(256, 2) void attn_kernel(const bf16* __restrict__ QKV,
                                                      const bf16* __restrict__ Vt,
                                                      bf16* __restrict__ aout) {
  const int qt = gridDim.x - 1 - blockIdx.x;  // 0..7, long blocks first
  const int h = blockIdx.y;
  const int b = blockIdx.z;
  const int tid = threadIdx.x;
  const int l = tid & 63;
  const int w = tid >> 6;
  const int ql = l & 31;   // q within wave tile; also d-col / k-row in frags
  const int hi = l >> 5;

  __shared__ char lds[65536];

  const char* qkv_b = (const char*)QKV + (size_t)b * S_ * (NQKV_ * 2);
  const char* vt_b = (const char*)Vt + (size_t)b * D_ * S_ * 2;

  // staging address tables (pre-swizzled source, linear LDS dest)
  int kr[4], kc[4], vr[4], vc[4];
#pragma unroll
  for (int o = 0; o < 4; ++o) {
    const int X = w * 4096 + o * 1024 + l * 16;
    const int r = X >> 8;
    kr[o] = r;
    kc[o] = (X & 255) ^ ((r & 15) << 4);
    const int d = X >> 7;
    vr[o] = d;
    vc[o] = (X & 127) ^ ((d & 7) << 4);
  }

#define STAGE_K(kb_off, kt_)                                                          \
  _Pragma("unroll") for (int o = 0; o < 4; ++o)                                       \
      gload_lds16(qkv_b + (size_t)((kt_) * 64 + kr[o]) * (NQKV_ * 2) + HID_ * 2 +     \
                      kc[o],                                                          \
                  lds + (kb_off) + w * 4096 + o * 1024);
#define STAGE_V(vb_off, kt_)                                                          \
  _Pragma("unroll") for (int o = 0; o < 4; ++o)                                       \
      gload_lds16(vt_b + (size_t)vr[o] * (S_ * 2) + (kt_) * 128 + vc[o],              \
                  lds + (vb_off) + w * 4096 + o * 1024);

  // ---- stage Q (128 rows x 256B) into lds[0,32K), read frags ----
#pragma unroll
  for (int o = 0; o < 8; ++o) {
    const int X = w * 8192 + o * 1024 + l * 16;
    const int r = X >> 8;
    const int cb = (X & 255) ^ ((r & 15) << 4);
    gload_lds16(qkv_b + (size_t)(qt * 128 + r) * (NQKV_ * 2) + h * 256 + cb, lds + X);
  }
  asm volatile("s_waitcnt vmcnt(0)" ::: "memory");
  __builtin_amdgcn_s_barrier();

  bf16x8 qf[8];
  {
    const int qrow = w * 32 + ql;
#pragma unroll
    for (int ds = 0; ds < 8; ++ds)
      qf[ds] = *(const bf16x8*)(lds + qrow * 256 + ((ds * 32 + hi * 16) ^ ((qrow & 15) << 4)));
  }
  asm volatile("s_waitcnt lgkmcnt(0)" ::: "memory");
  __builtin_amdgcn_sched_barrier(0);
  __builtin_amdgcn_s_barrier();  // all waves done reading Q before tile-0 staging

  // ---- prologue: stage tile 0 into buffer 0 ----
  STAGE_K(0, 0);
  STAGE_V(32768, 0);

  const float scale = 0.08838834764831845f;
  const int qglob = qt * 128 + w * 32 + ql;
  float mrun = -1e30f, lrun = 0.f;
  f32x16 Oacc[4] = {};

  const int nkt = 2 * qt + 2;
  for (int kt = 0; kt < nkt; ++kt) {
    const int cur = kt & 1;
    const int kb = cur * 16384;
    const int vb = 32768 + cur * 16384;
    if (kt < nkt - 1) {
      STAGE_K(kb ^ 16384, kt + 1);
      STAGE_V(vb ^ 16384, kt + 1);
      asm volatile("s_waitcnt vmcnt(8)" ::: "memory");
    } else {
      asm volatile("s_waitcnt vmcnt(0)" ::: "memory");
    }
    __builtin_amdgcn_s_barrier();
    __builtin_amdgcn_sched_barrier(0);

    const bool skip = (64 * kt >= 128 * qt + 32 * w + 32);  // tile fully above diagonal
    if (!skip) {
      const bool need_mask = (64 * kt + 63 > 128 * qt + 32 * w);

      // ---- QK^T: S^T[k][q], two 32-k halves ----
      f32x16 s0 = {}, s1 = {};
      __builtin_amdgcn_s_setprio(1);
#pragma unroll
      for (int ds = 0; ds < 8; ++ds) {
        const int krow = ql;  // kh=0
        const bf16x8 kf =
            *(const bf16x8*)(lds + kb + krow * 256 + ((ds * 32 + hi * 16) ^ ((krow & 15) << 4)));
        s0 = __builtin_amdgcn_mfma_f32_32x32x16_bf16(kf, qf[ds], s0, 0, 0, 0);
      }
#pragma unroll
      for (int ds = 0; ds < 8; ++ds) {
        const int krow = 32 + ql;  // kh=1
        const bf16x8 kf =
            *(const bf16x8*)(lds + kb + krow * 256 + ((ds * 32 + hi * 16) ^ ((krow & 15) << 4)));
        s1 = __builtin_amdgcn_mfma_f32_32x32x16_bf16(kf, qf[ds], s1, 0, 0, 0);
      }
      __builtin_amdgcn_s_setprio(0);

      // ---- scale + causal mask (k(reg) = (reg&3)+8*(reg>>2)+4*hi) ----
#pragma unroll
      for (int r = 0; r < 16; ++r) {
        const int krl = (r & 3) + 8 * (r >> 2) + 4 * hi;
        float v0 = s0[r] * scale, v1 = s1[r] * scale;
        if (need_mask) {
          if (64 * kt + krl > qglob) v0 = -1e30f;
          if (64 * kt + 32 + krl > qglob) v1 = -1e30f;
        }
        s0[r] = v0;
        s1[r] = v1;
      }

      // ---- row max: in-lane tree + one cross-half exchange ----
      float a0 = -1e30f, a1 = -1e30f, a2 = -1e30f, a3 = -1e30f;
#pragma unroll
      for (int r = 0; r < 16; r += 4) {
        a0 = fmaxf(a0, fmaxf(s0[r], s1[r]));
        a1 = fmaxf(a1, fmaxf(s0[r + 1], s1[r + 1]));
        a2 = fmaxf(a2, fmaxf(s0[r + 2], s1[r + 2]));
        a3 = fmaxf(a3, fmaxf(s0[r + 3], s1[r + 3]));
      }
      float tmax = fmaxf(fmaxf(a0, a1), fmaxf(a2, a3));
      tmax = fmaxf(tmax, __shfl_xor(tmax, 32));

      // ---- defer-max (T13): rescale only when max grew > 8 ----
      if (!__all(tmax <= mrun + 8.f)) {
        const float mn = fmaxf(mrun, tmax);
        const float corr = __expf(mrun - mn);
        mrun = mn;
        lrun *= corr;
#pragma unroll
        for (int r = 0; r < 16; ++r) {
          const float cq = __shfl(corr, (r & 3) + 8 * (r >> 2) + 4 * hi);
#pragma unroll
          for (int dt = 0; dt < 4; ++dt) Oacc[dt][r] *= cq;
        }
      }

      // ---- P = exp(S - mrun), row sum ----
      float b0 = 0.f, b1 = 0.f, b2 = 0.f, b3 = 0.f;
#pragma unroll
      for (int r = 0; r < 16; r += 4) {
        s0[r] = __expf(s0[r] - mrun);
        s1[r] = __expf(s1[r] - mrun);
        b0 += s0[r] + s1[r];
        s0[r + 1] = __expf(s0[r + 1] - mrun);
        s1[r + 1] = __expf(s1[r + 1] - mrun);
        b1 += s0[r + 1] + s1[r + 1];
        s0[r + 2] = __expf(s0[r + 2] - mrun);
        s1[r + 2] = __expf(s1[r + 2] - mrun);
        b2 += s0[r + 2] + s1[r + 2];
        s0[r + 3] = __expf(s0[r + 3] - mrun);
        s1[r + 3] = __expf(s1[r + 3] - mrun);
        b3 += s0[r + 3] + s1[r + 3];
      }
      float rs = (b0 + b1) + (b2 + b3);
      rs += __shfl_xor(rs, 32);
      lrun += rs;

      // ---- pack P to bf16 A-frags (cross-half exchange via shfl_xor 32) ----
      unsigned c[16], xc[16];
#pragma unroll
      for (int m = 0; m < 8; ++m) {
        c[m] = pack_bf16(s0[2 * m], s0[2 * m + 1]);
        c[8 + m] = pack_bf16(s1[2 * m], s1[2 * m + 1]);
      }
#pragma unroll
      for (int m = 0; m < 16; ++m) xc[m] = (unsigned)__shfl_xor((int)c[m], 32);

      bf16x8 pa[4];
#pragma unroll
      for (int kh = 0; kh < 2; ++kh) {
        const int base = 8 * kh;
        u32x4 f0, f1;
        f0[0] = hi ? xc[base + 2] : c[base + 0];
        f0[1] = hi ? xc[base + 3] : c[base + 1];
        f0[2] = hi ? c[base + 2] : xc[base + 0];
        f0[3] = hi ? c[base + 3] : xc[base + 1];
        f1[0] = hi ? xc[base + 6] : c[base + 4];
        f1[1] = hi ? xc[base + 7] : c[base + 5];
        f1[2] = hi ? c[base + 6] : xc[base + 4];
        f1[3] = hi ? c[base + 7] : xc[base + 5];
        pa[2 * kh] = __builtin_bit_cast(bf16x8, f0);
        pa[2 * kh + 1] = __builtin_bit_cast(bf16x8, f1);
      }

      // ---- PV: O[q][d] += P·V ----
      __builtin_amdgcn_s_setprio(1);
#pragma unroll
      for (int dt = 0; dt < 4; ++dt) {
        const int vrow = dt * 32 + ql;
#pragma unroll
        for (int ks = 0; ks < 4; ++ks) {
          const bf16x8 vf =
              *(const bf16x8*)(lds + vb + vrow * 128 + ((ks * 32 + hi * 16) ^ ((vrow & 7) << 4)));
          Oacc[dt] = __builtin_amdgcn_mfma_f32_32x32x16_bf16(pa[ks], vf, Oacc[dt], 0, 0, 0);
        }
      }
      __builtin_amdgcn_s_setprio(0);
    }
    __builtin_amdgcn_s_barrier();  // all waves done with cur before restage
  }

  // ---- epilogue: O / lrun; O row q(reg) = (reg&3)+8*(reg>>2)+4*hi ----
#pragma unroll
  for (int r = 0; r < 16; ++r) {
    const int qi = (r & 3) + 8 * (r >> 2) + 4 * hi;
    const float lr = __shfl(lrun, qi);
    const float inv = 1.0f / lr;
    const int token = b * S_ + qt * 128 + w * 32 + qi;
    bf16* orow = aout + (size_t)token * HID_ + h * D_;
#pragma unroll
    for (int dt = 0; dt < 4; ++dt)
      orow[dt * 32 + ql] = __float2bfloat16(Oacc[dt][r] * inv);
  }
#undef STAGE_K
#undef STAGE_V
}

extern "C" void kernel_launch(void* const* d_in, const int* in_sizes, int n_in,
                              void* d_out, int out_size, void* d_ws, size_t ws_size,
                              hipStream_t stream) {
  const float* hidden = (const float*)d_in[0];
  const float* w_attn = (const float*)d_in[1];
  const float* b_attn = (const float*)d_in[2];
  const float* w_proj = (const float*)d_in[3];
  const float* b_proj = (const float*)d_in[4];

  char* ws = (char*)d_ws;
  char* dob = (char*)d_out;

  // ws: [0,33.5M) Xbf (bf16 hidden, later attn out); [33.5M,42M) WpT
  bf16* Xbf = (bf16*)ws;
  bf16* WpT = (bf16*)(ws + 33554432);
  // d_out as scratch (fully overwritten by GEMM2):
  // [0,37.75M) QKV bf16; [37.75M,47.2M) WaT; [48M,50M) Vt bf16
  bf16* QKV = (bf16*)dob;
  bf16* WaT = (bf16*)(dob + 37748736);
  bf16* Vt = (bf16*)(dob + 50331648);

  cast_bf16_kernel<<<(T_ * HID_) / 8 / 256, 256, 0, stream>>>(hidden, Xbf, (T_ * HID_) / 8);
  transpose_cast_kernel<<<dim3(NQKV_ / 32, HID_ / 32), 256, 0, stream>>>(w_attn, WaT, HID_, NQKV_);
  transpose_cast_kernel<<<dim3(HID_ / 32, HID_ / 32), 256, 0, stream>>>(w_proj, WpT, HID_, HID_);

  gemm_kernel<false><<<dim3(NQKV_ / 128, T_ / 128), 256, 0, stream>>>(
      Xbf, WaT, b_attn, QKV, T_, NQKV_, HID_);

  transpose_v_kernel<<<dim3(S_ / 64, D_ / 64, B_), 256, 0, stream>>>(QKV, Vt);

  attn_kernel<<<dim3(S_ / 128, H_, B_), 256, 0, stream>>>(QKV, Vt, Xbf);

  gemm_kernel<true><<<dim3(HID_ / 128, T_ / 128), 256, 0, stream>>>(
      Xbf, WpT, b_proj, (float*)d_out, T_, HID_, HID_);
}

// Round 12
// 302.067 us; speedup vs baseline: 2.1361x; 1.3152x over previous
//
#include <hip/hip_runtime.h>
#include <hip/hip_bf16.h>

typedef __hip_bfloat16 bf16;
typedef __attribute__((ext_vector_type(8))) __bf16 bf16x8;
typedef __attribute__((ext_vector_type(4))) float f32x4;
typedef __attribute__((ext_vector_type(16))) float f32x16;
typedef __attribute__((ext_vector_type(8))) short s16x8;
typedef __attribute__((ext_vector_type(4))) unsigned u32x4;

#define B_    8
#define S_    1024
#define H_    16
#define D_    128
#define HID_  2048
#define NQKV_ 2304
#define T_    8192

__device__ __forceinline__ void gload_lds16(const void* g, void* l) {
  __builtin_amdgcn_global_load_lds((const __attribute__((address_space(1))) void*)g,
                                   (__attribute__((address_space(3))) void*)l, 16, 0, 0);
}

__device__ __forceinline__ unsigned pack_bf16(float lo, float hi) {
  return ((unsigned)__bfloat16_as_ushort(__float2bfloat16(hi)) << 16) |
         (unsigned)__bfloat16_as_ushort(__float2bfloat16(lo));
}

// ---------------- cast fp32 -> bf16, 8 elems/thread ----------------
__global__ void cast_bf16_kernel(const float* __restrict__ src, bf16* __restrict__ dst, int n8) {
  const int i = blockIdx.x * 256 + threadIdx.x;
  if (i >= n8) return;
  const float4 a = ((const float4*)src)[2 * i];
  const float4 b = ((const float4*)src)[2 * i + 1];
  s16x8 o;
  o[0] = (short)__bfloat16_as_ushort(__float2bfloat16(a.x));
  o[1] = (short)__bfloat16_as_ushort(__float2bfloat16(a.y));
  o[2] = (short)__bfloat16_as_ushort(__float2bfloat16(a.z));
  o[3] = (short)__bfloat16_as_ushort(__float2bfloat16(a.w));
  o[4] = (short)__bfloat16_as_ushort(__float2bfloat16(b.x));
  o[5] = (short)__bfloat16_as_ushort(__float2bfloat16(b.y));
  o[6] = (short)__bfloat16_as_ushort(__float2bfloat16(b.z));
  o[7] = (short)__bfloat16_as_ushort(__float2bfloat16(b.w));
  ((s16x8*)dst)[i] = o;
}

// ------------- transpose + cast: src (R x C) f32 -> dst (C x R) bf16 -------------
__global__ void transpose_cast_kernel(const float* __restrict__ src, bf16* __restrict__ dst,
                                      int R, int C) {
  __shared__ float tile[32][33];
  const int tx = threadIdx.x & 31, ty = threadIdx.x >> 5;
  const int rt = blockIdx.y * 32, ct = blockIdx.x * 32;
#pragma unroll
  for (int k = 0; k < 4; ++k)
    tile[ty + 8 * k][tx] = src[(size_t)(rt + ty + 8 * k) * C + ct + tx];
  __syncthreads();
#pragma unroll
  for (int k = 0; k < 4; ++k)
    dst[(size_t)(ct + ty + 8 * k) * R + rt + tx] = __float2bfloat16(tile[tx][ty + 8 * k]);
}

// ------------- V transpose: QKV V-cols -> Vt[b][d][k] bf16 -------------
__global__ void transpose_v_kernel(const bf16* __restrict__ QKV, bf16* __restrict__ Vt) {
  __shared__ short t[64][72];
  const int kt = blockIdx.x, dt = blockIdx.y, b = blockIdx.z;
  const int r = threadIdx.x >> 3;
  const int c8 = (threadIdx.x & 7) * 8;
#pragma unroll
  for (int p = 0; p < 2; ++p) {
    const int row = p * 32 + r;
    const s16x8 v = *(const s16x8*)(QKV + (size_t)(b * S_ + kt * 64 + row) * NQKV_ +
                                    HID_ + D_ + dt * 64 + c8);
    *(s16x8*)&t[row][c8] = v;
  }
  __syncthreads();
#pragma unroll
  for (int p = 0; p < 2; ++p) {
    const int drow = p * 32 + r;
    s16x8 o;
#pragma unroll
    for (int j = 0; j < 8; ++j) o[j] = t[c8 + j][drow];
    *(s16x8*)(Vt + (size_t)(b * D_ + dt * 64 + drow) * S_ + kt * 64 + c8) = o;
  }
}

// ------------- GEMM v2: 128x128 tile, BK=64, double-buffered, counted vmcnt -------------
// A (MxK) * Bt(NxK)^T + bias -> C (MxN). LDS 64KB: buf b @ b*32768 {A 128x128B, B @+16384}.
// Both-sides XOR swizzle (row&7)<<4: pre-swizzled global source + swizzled ds_read (rule 21).
// XCD-aware bijective block swizzle (nwg % 8 == 0 for both GEMMs).
template <bool OUT_F32>
__global__ __launch_bounds__(256, 2) void gemm_kernel(const bf16* __restrict__ A,
                                                      const bf16* __restrict__ Bt,
                                                      const float* __restrict__ bias,
                                                      void* __restrict__ Cout,
                                                      int M, int N, int K) {
  __shared__ char lds[65536];
  const int tid = threadIdx.x;
  const int lane = tid & 63;
  const int wave = tid >> 6;

  // XCD swizzle: same-XCD blocks get a contiguous bm-major chunk (L2 A-panel reuse)
  const int gx = gridDim.x;
  const int lid = blockIdx.y * gx + blockIdx.x;
  const int cpx = (gx * gridDim.y) >> 3;
  const int swz = (lid & 7) * cpx + (lid >> 3);
  const int bn = swz % gx, bm = swz / gx;

  const int lrow = lane & 15, lk = lane >> 4;
  const int rbase = (wave >> 1) * 64;
  const int nbase = (wave & 1) * 64;
  f32x4 acc[4][4] = {};

  // staging tables: 4 x 16B chunks per thread per matrix; source pre-swizzled
  int srow[4], scol[4];
#pragma unroll
  for (int o = 0; o < 4; ++o) {
    const int X = o * 4096 + tid * 16;
    const int r = X >> 7, Y = X & 127;
    srow[o] = r;
    scol[o] = Y ^ ((r & 7) << 4);
  }

  const char* Ab = (const char*)A + (size_t)(bm * 128) * K * 2;
  const char* Bb = (const char*)Bt + (size_t)(bn * 128) * K * 2;

#define G_STAGE(buf, kt_)                                                              \
  _Pragma("unroll") for (int o = 0; o < 4; ++o)                                        \
      gload_lds16(Ab + (size_t)srow[o] * (K * 2) + (size_t)(kt_) * 128 + scol[o],      \
                  lds + (buf) + o * 4096 + tid * 16);                                  \
  _Pragma("unroll") for (int o = 0; o < 4; ++o)                                        \
      gload_lds16(Bb + (size_t)srow[o] * (K * 2) + (size_t)(kt_) * 128 + scol[o],      \
                  lds + (buf) + 16384 + o * 4096 + tid * 16);

  // prologue: stage K-tile 0 into buffer 0
  G_STAGE(0, 0);

  const int nkt = K >> 6;
  for (int kt = 0; kt < nkt; ++kt) {
    const int cur = (kt & 1) * 32768;
    if (kt < nkt - 1) {
      G_STAGE(cur ^ 32768, kt + 1);
      asm volatile("s_waitcnt vmcnt(8)" ::: "memory");  // cur tile's 8 loads landed
    } else {
      asm volatile("s_waitcnt vmcnt(0)" ::: "memory");
    }
    __builtin_amdgcn_s_barrier();

    bf16x8 af[4][2], bfr[4][2];
#pragma unroll
    for (int mi = 0; mi < 4; ++mi) {
      const int row = rbase + mi * 16 + lrow;
#pragma unroll
      for (int kk = 0; kk < 2; ++kk)
        af[mi][kk] =
            *(const bf16x8*)(lds + cur + row * 128 + ((kk * 64 + lk * 16) ^ ((row & 7) << 4)));
    }
#pragma unroll
    for (int ni = 0; ni < 4; ++ni) {
      const int row = nbase + ni * 16 + lrow;
#pragma unroll
      for (int kk = 0; kk < 2; ++kk)
        bfr[ni][kk] = *(const bf16x8*)(lds + cur + 16384 + row * 128 +
                                       ((kk * 64 + lk * 16) ^ ((row & 7) << 4)));
    }
#pragma unroll
    for (int kk = 0; kk < 2; ++kk)
#pragma unroll
      for (int mi = 0; mi < 4; ++mi)
#pragma unroll
        for (int ni = 0; ni < 4; ++ni)
          acc[mi][ni] =
              __builtin_amdgcn_mfma_f32_16x16x32_bf16(af[mi][kk], bfr[ni][kk], acc[mi][ni], 0, 0, 0);
    __builtin_amdgcn_s_barrier();  // all waves done reading cur before it's restaged
  }
#undef G_STAGE

#pragma unroll
  for (int ni = 0; ni < 4; ++ni) {
    const int col = bn * 128 + nbase + ni * 16 + lrow;
    const float bv = bias[col];
#pragma unroll
    for (int mi = 0; mi < 4; ++mi) {
      const int row0 = bm * 128 + rbase + mi * 16 + lk * 4;
#pragma unroll
      for (int r = 0; r < 4; ++r) {
        const float v = acc[mi][ni][r] + bv;
        if (OUT_F32)
          ((float*)Cout)[(size_t)(row0 + r) * N + col] = v;
        else
          ((bf16*)Cout)[(size_t)(row0 + r) * N + col] = __float2bfloat16(v);
      }
    }
  }
}

// ------------- causal MQA flash attention v5 (unchanged from round 11) -------------
__global__ __launch_bounds__(256, 2) void attn_kernel(const bf16* __restrict__ QKV,
                                                      const bf16* __restrict__ Vt,
                                                      bf16* __restrict__ aout) {
  const int qt = gridDim.x - 1 - blockIdx.x;
  const int h = blockIdx.y;
  const int b = blockIdx.z;
  const int tid = threadIdx.x;
  const int l = tid & 63;
  const int w = tid >> 6;
  const int ql = l & 31;
  const int hi = l >> 5;

  __shared__ char lds[65536];

  const char* qkv_b = (const char*)QKV + (size_t)b * S_ * (NQKV_ * 2);
  const char* vt_b = (const char*)Vt + (size_t)b * D_ * S_ * 2;

  int kr[4], kc[4], vr[4], vc[4];
#pragma unroll
  for (int o = 0; o < 4; ++o) {
    const int X = w * 4096 + o * 1024 + l * 16;
    const int r = X >> 8;
    kr[o] = r;
    kc[o] = (X & 255) ^ ((r & 15) << 4);
    const int d = X >> 7;
    vr[o] = d;
    vc[o] = (X & 127) ^ ((d & 7) << 4);
  }

#define STAGE_K(kb_off, kt_)                                                          \
  _Pragma("unroll") for (int o = 0; o < 4; ++o)                                       \
      gload_lds16(qkv_b + (size_t)((kt_) * 64 + kr[o]) * (NQKV_ * 2) + HID_ * 2 +     \
                      kc[o],                                                          \
                  lds + (kb_off) + w * 4096 + o * 1024);
#define STAGE_V(vb_off, kt_)                                                          \
  _Pragma("unroll") for (int o = 0; o < 4; ++o)                                       \
      gload_lds16(vt_b + (size_t)vr[o] * (S_ * 2) + (kt_) * 128 + vc[o],              \
                  lds + (vb_off) + w * 4096 + o * 1024);

#pragma unroll
  for (int o = 0; o < 8; ++o) {
    const int X = w * 8192 + o * 1024 + l * 16;
    const int r = X >> 8;
    const int cb = (X & 255) ^ ((r & 15) << 4);
    gload_lds16(qkv_b + (size_t)(qt * 128 + r) * (NQKV_ * 2) + h * 256 + cb, lds + X);
  }
  asm volatile("s_waitcnt vmcnt(0)" ::: "memory");
  __builtin_amdgcn_s_barrier();

  bf16x8 qf[8];
  {
    const int qrow = w * 32 + ql;
#pragma unroll
    for (int ds = 0; ds < 8; ++ds)
      qf[ds] = *(const bf16x8*)(lds + qrow * 256 + ((ds * 32 + hi * 16) ^ ((qrow & 15) << 4)));
  }
  asm volatile("s_waitcnt lgkmcnt(0)" ::: "memory");
  __builtin_amdgcn_sched_barrier(0);
  __builtin_amdgcn_s_barrier();

  STAGE_K(0, 0);
  STAGE_V(32768, 0);

  const float scale = 0.08838834764831845f;
  const int qglob = qt * 128 + w * 32 + ql;
  float mrun = -1e30f, lrun = 0.f;
  f32x16 Oacc[4] = {};

  const int nkt = 2 * qt + 2;
  for (int kt = 0; kt < nkt; ++kt) {
    const int cur = kt & 1;
    const int kb = cur * 16384;
    const int vb = 32768 + cur * 16384;
    if (kt < nkt - 1) {
      STAGE_K(kb ^ 16384, kt + 1);
      STAGE_V(vb ^ 16384, kt + 1);
      asm volatile("s_waitcnt vmcnt(8)" ::: "memory");
    } else {
      asm volatile("s_waitcnt vmcnt(0)" ::: "memory");
    }
    __builtin_amdgcn_s_barrier();
    __builtin_amdgcn_sched_barrier(0);

    const bool skip = (64 * kt >= 128 * qt + 32 * w + 32);
    if (!skip) {
      const bool need_mask = (64 * kt + 63 > 128 * qt + 32 * w);

      f32x16 s0 = {}, s1 = {};
      __builtin_amdgcn_s_setprio(1);
#pragma unroll
      for (int ds = 0; ds < 8; ++ds) {
        const int krow = ql;
        const bf16x8 kf =
            *(const bf16x8*)(lds + kb + krow * 256 + ((ds * 32 + hi * 16) ^ ((krow & 15) << 4)));
        s0 = __builtin_amdgcn_mfma_f32_32x32x16_bf16(kf, qf[ds], s0, 0, 0, 0);
      }
#pragma unroll
      for (int ds = 0; ds < 8; ++ds) {
        const int krow = 32 + ql;
        const bf16x8 kf =
            *(const bf16x8*)(lds + kb + krow * 256 + ((ds * 32 + hi * 16) ^ ((krow & 15) << 4)));
        s1 = __builtin_amdgcn_mfma_f32_32x32x16_bf16(kf, qf[ds], s1, 0, 0, 0);
      }
      __builtin_amdgcn_s_setprio(0);

#pragma unroll
      for (int r = 0; r < 16; ++r) {
        const int krl = (r & 3) + 8 * (r >> 2) + 4 * hi;
        float v0 = s0[r] * scale, v1 = s1[r] * scale;
        if (need_mask) {
          if (64 * kt + krl > qglob) v0 = -1e30f;
          if (64 * kt + 32 + krl > qglob) v1 = -1e30f;
        }
        s0[r] = v0;
        s1[r] = v1;
      }

      float a0 = -1e30f, a1 = -1e30f, a2 = -1e30f, a3 = -1e30f;
#pragma unroll
      for (int r = 0; r < 16; r += 4) {
        a0 = fmaxf(a0, fmaxf(s0[r], s1[r]));
        a1 = fmaxf(a1, fmaxf(s0[r + 1], s1[r + 1]));
        a2 = fmaxf(a2, fmaxf(s0[r + 2], s1[r + 2]));
        a3 = fmaxf(a3, fmaxf(s0[r + 3], s1[r + 3]));
      }
      float tmax = fmaxf(fmaxf(a0, a1), fmaxf(a2, a3));
      tmax = fmaxf(tmax, __shfl_xor(tmax, 32));

      if (!__all(tmax <= mrun + 8.f)) {
        const float mn = fmaxf(mrun, tmax);
        const float corr = __expf(mrun - mn);
        mrun = mn;
        lrun *= corr;
#pragma unroll
        for (int r = 0; r < 16; ++r) {
          const float cq = __shfl(corr, (r & 3) + 8 * (r >> 2) + 4 * hi);
#pragma unroll
          for (int dt = 0; dt < 4; ++dt) Oacc[dt][r] *= cq;
        }
      }

      float b0 = 0.f, b1 = 0.f, b2 = 0.f, b3 = 0.f;
#pragma unroll
      for (int r = 0; r < 16; r += 4) {
        s0[r] = __expf(s0[r] - mrun);
        s1[r] = __expf(s1[r] - mrun);
        b0 += s0[r] + s1[r];
        s0[r + 1] = __expf(s0[r + 1] - mrun);
        s1[r + 1] = __expf(s1[r + 1] - mrun);
        b1 += s0[r + 1] + s1[r + 1];
        s0[r + 2] = __expf(s0[r + 2] - mrun);
        s1[r + 2] = __expf(s1[r + 2] - mrun);
        b2 += s0[r + 2] + s1[r + 2];
        s0[r + 3] = __expf(s0[r + 3] - mrun);
        s1[r + 3] = __expf(s1[r + 3] - mrun);
        b3 += s0[r + 3] + s1[r + 3];
      }
      float rs = (b0 + b1) + (b2 + b3);
      rs += __shfl_xor(rs, 32);
      lrun += rs;

      unsigned c[16], xc[16];
#pragma unroll
      for (int m = 0; m < 8; ++m) {
        c[m] = pack_bf16(s0[2 * m], s0[2 * m + 1]);
        c[8 + m] = pack_bf16(s1[2 * m], s1[2 * m + 1]);
      }
#pragma unroll
      for (int m = 0; m < 16; ++m) xc[m] = (unsigned)__shfl_xor((int)c[m], 32);

      bf16x8 pa[4];
#pragma unroll
      for (int kh = 0; kh < 2; ++kh) {
        const int base = 8 * kh;
        u32x4 f0, f1;
        f0[0] = hi ? xc[base + 2] : c[base + 0];
        f0[1] = hi ? xc[base + 3] : c[base + 1];
        f0[2] = hi ? c[base + 2] : xc[base + 0];
        f0[3] = hi ? c[base + 3] : xc[base + 1];
        f1[0] = hi ? xc[base + 6] : c[base + 4];
        f1[1] = hi ? xc[base + 7] : c[base + 5];
        f1[2] = hi ? c[base + 6] : xc[base + 4];
        f1[3] = hi ? c[base + 7] : xc[base + 5];
        pa[2 * kh] = __builtin_bit_cast(bf16x8, f0);
        pa[2 * kh + 1] = __builtin_bit_cast(bf16x8, f1);
      }

      __builtin_amdgcn_s_setprio(1);
#pragma unroll
      for (int dt = 0; dt < 4; ++dt) {
        const int vrow = dt * 32 + ql;
#pragma unroll
        for (int ks = 0; ks < 4; ++ks) {
          const bf16x8 vf =
              *(const bf16x8*)(lds + vb + vrow * 128 + ((ks * 32 + hi * 16) ^ ((vrow & 7) << 4)));
          Oacc[dt] = __builtin_amdgcn_mfma_f32_32x32x16_bf16(pa[ks], vf, Oacc[dt], 0, 0, 0);
        }
      }
      __builtin_amdgcn_s_setprio(0);
    }
    __builtin_amdgcn_s_barrier();
  }

#pragma unroll
  for (int r = 0; r < 16; ++r) {
    const int qi = (r & 3) + 8 * (r >> 2) + 4 * hi;
    const float lr = __shfl(lrun, qi);
    const float inv = 1.0f / lr;
    const int token = b * S_ + qt * 128 + w * 32 + qi;
    bf16* orow = aout + (size_t)token * HID_ + h * D_;
#pragma unroll
    for (int dt = 0; dt < 4; ++dt)
      orow[dt * 32 + ql] = __float2bfloat16(Oacc[dt][r] * inv);
  }
#undef STAGE_K
#undef STAGE_V
}

extern "C" void kernel_launch(void* const* d_in, const int* in_sizes, int n_in,
                              void* d_out, int out_size, void* d_ws, size_t ws_size,
                              hipStream_t stream) {
  const float* hidden = (const float*)d_in[0];
  const float* w_attn = (const float*)d_in[1];
  const float* b_attn = (const float*)d_in[2];
  const float* w_proj = (const float*)d_in[3];
  const float* b_proj = (const float*)d_in[4];

  char* ws = (char*)d_ws;
  char* dob = (char*)d_out;

  bf16* Xbf = (bf16*)ws;
  bf16* WpT = (bf16*)(ws + 33554432);
  bf16* QKV = (bf16*)dob;
  bf16* WaT = (bf16*)(dob + 37748736);
  bf16* Vt = (bf16*)(dob + 50331648);

  cast_bf16_kernel<<<(T_ * HID_) / 8 / 256, 256, 0, stream>>>(hidden, Xbf, (T_ * HID_) / 8);
  transpose_cast_kernel<<<dim3(NQKV_ / 32, HID_ / 32), 256, 0, stream>>>(w_attn, WaT, HID_, NQKV_);
  transpose_cast_kernel<<<dim3(HID_ / 32, HID_ / 32), 256, 0, stream>>>(w_proj, WpT, HID_, HID_);

  gemm_kernel<false><<<dim3(NQKV_ / 128, T_ / 128), 256, 0, stream>>>(
      Xbf, WaT, b_attn, QKV, T_, NQKV_, HID_);

  transpose_v_kernel<<<dim3(S_ / 64, D_ / 64, B_), 256, 0, stream>>>(QKV, Vt);

  attn_kernel<<<dim3(S_ / 128, H_, B_), 256, 0, stream>>>(QKV, Vt, Xbf);

  gemm_kernel<true><<<dim3(HID_ / 128, T_ / 128), 256, 0, stream>>>(
      Xbf, WpT, b_proj, (float*)d_out, T_, HID_, HID_);
}